// Round 5
// baseline (547.809 us; speedup 1.0000x reference)
//
#include <hip/hip_runtime.h>

#define NGR 8192
#define NN 54
#define NE 144
#define FN 18
#define FE 5
#define HD 48
#define NOUT 80
#define NL 3
#define HS 56    // h/agg row stride (shorts): 112B
#define MS 72    // m row stride (shorts): 144B
#define TS 152   // m_t row stride (shorts): 304B
#define NFRAG 102

typedef short v8s __attribute__((ext_vector_type(8)));
typedef float v4f __attribute__((ext_vector_type(4)));

#define MFMA(a, b, c) __builtin_amdgcn_mfma_f32_16x16x32_bf16((a), (b), (c), 0, 0, 0)

static __device__ __forceinline__ float mish_f(float x) {
  // x * u/(u+2), u = t(t+2), t = e^min(x,30): exact mish for x<=30, ==x beyond
  float t = __expf(fminf(x, 30.f));
  float u = t * (t + 2.f);
  return x * u * __builtin_amdgcn_rcpf(u + 2.f);
}
static __device__ __forceinline__ short f2b(float x) {  // fp32->bf16 RNE (setup/scalar paths)
  union { float f; unsigned u; } v; v.f = x;
  unsigned r = v.u + 0x7FFFu + ((v.u >> 16) & 1u);
  return (short)(r >> 16);
}
static __device__ __forceinline__ float b2f(short s) {
  union { unsigned u; float f; } v; v.u = ((unsigned)(unsigned short)s) << 16;
  return v.f;
}
static __device__ __forceinline__ unsigned cvt_pk(float lo, float hi) {
  unsigned r;
  asm("v_cvt_pk_bf16_f32 %0, %1, %2" : "=v"(r) : "v"(lo), "v"(hi));
  return r;
}
static __device__ __forceinline__ void st4v(short* p, v4f y) {   // 4 ch -> b64 store
  uint2 u; u.x = cvt_pk(y[0], y[1]); u.y = cvt_pk(y[2], y[3]);
  *(uint2*)p = u;
}
static __device__ __forceinline__ void st4m(short* p, v4f c) {   // mish then b64 store
  v4f y; y[0] = mish_f(c[0]); y[1] = mish_f(c[1]); y[2] = mish_f(c[2]); y[3] = mish_f(c[3]);
  st4v(p, y);
}

// ---------------- setup: weight fragment prepack + folded msg bias (round-4-proven, 102 frags) ----------------
__global__ void gnn_setup(const float* __restrict__ w_node,
                          const float* __restrict__ w_edge,
                          const float* __restrict__ b_edge,
                          const float* __restrict__ msg_w1,
                          const float* __restrict__ msg_b1,
                          const float* __restrict__ msg_w2,
                          const float* __restrict__ upd_w1,
                          const float* __restrict__ upd_w2,
                          float* __restrict__ mb1, short* __restrict__ frags) {
  const int t = threadIdx.x;
  if (blockIdx.x == 0) {
    for (int idx = t; idx < NL * HD; idx += 256) {
      int l = idx / HD, c = idx % HD;
      float s = msg_b1[l * HD + c];
      for (int k = 0; k < HD; ++k)
        s += b_edge[k] * msg_w1[(l * 144 + 96 + k) * HD + c];
      mb1[idx] = s;
    }
  }
  // frag f, lane, elem j holds W[ks*32 + (lane>>4)*8 + j][ct*16 + (lane&15)]
  for (int eid = blockIdx.x * 256 + t; eid < NFRAG * 512; eid += gridDim.x * 256) {
    int f = eid >> 9, r = eid & 511;
    int lane = r >> 3, j = r & 7;
    int kk = ((lane >> 4) << 3) + j;
    int colq = lane & 15;
    float val = 0.f;
    if (f < 3) {                          // w_node (K=18 pad 32), ct=f
      int c = f * 16 + colq;
      if (kk < FN) val = w_node[kk * HD + c];
    } else {
      int g = f - 3, l = g / 33, o = g % 33;
      if (o < 9) {                        // msg_w1 rows 0..95
        int ks = o / 3, ct = o % 3, c = ct * 16 + colq, k = ks * 32 + kk;
        val = msg_w1[(l * 144 + k) * HD + c];
      } else if (o < 12) {                // W_eff = w_edge @ msg_w1[96:144] (K=5 pad 32)
        int ct = o - 9, c = ct * 16 + colq;
        if (kk < FE) {
          float s = 0.f;
          for (int k2 = 0; k2 < HD; ++k2)
            s += w_edge[kk * HD + k2] * msg_w1[(l * 144 + 96 + k2) * HD + c];
          val = s;
        }
      } else if (o < 18) {                // msg_w2 (K=48 pad 64)
        int oo = o - 12, ks = oo / 3, ct = oo % 3, c = ct * 16 + colq, k = ks * 32 + kk;
        if (k < HD) val = msg_w2[(l * HD + k) * HD + c];
      } else if (o < 27) {                // upd_w1 (K=96)
        int oo = o - 18, ks = oo / 3, ct = oo % 3, c = ct * 16 + colq, k = ks * 32 + kk;
        val = upd_w1[(l * 96 + k) * HD + c];
      } else {                            // upd_w2 (K=48 pad 64)
        int oo = o - 27, ks = oo / 3, ct = oo % 3, c = ct * 16 + colq, k = ks * 32 + kk;
        if (k < HD) val = upd_w2[(l * HD + k) * HD + c];
      }
    }
    frags[eid] = f2b(val);
  }
}

// ---------------- main: one block (4 waves) per graph ----------------
__global__ __launch_bounds__(256, 4) void gnn_main(
    const float* __restrict__ nf, const float* __restrict__ efx,
    const float* __restrict__ b_node,
    const float* __restrict__ msg_b2,
    const float* __restrict__ upd_b1, const float* __restrict__ upd_b2,
    const float* __restrict__ ln_g, const float* __restrict__ ln_b,
    const float* __restrict__ w_out1, const float* __restrict__ b_out1,
    const float* __restrict__ w_out2, const float* __restrict__ b_out2,
    const int* __restrict__ edge_index,
    const float* __restrict__ mb1, const short* __restrict__ frags,
    float* __restrict__ out)
{
  __shared__ __align__(16) short h_s[NN][HS];        // 6048 B
  __shared__ __align__(16) short agg_s[NN][HS];      // 6048 B
  __shared__ __align__(16) short m_s[80][MS];        // 11520 B
  __shared__ __align__(16) short m_t[48 * TS + 8];   // 14608 B
  __shared__ int dst_s[NE];
  __shared__ float psum[96], pmax[96], pooled[96], o1[NOUT];

  const int b = blockIdx.x;
  const int t = threadIdx.x;
  const int lane = t & 63;
  const int w = t >> 6;
  const int lx = lane & 15;
  const int lg = lane >> 4;
  const int koff = lg << 3;
  const int lg4 = lg << 2;

#define LD8(f) (*(const v8s*)(frags + ((size_t)(f) << 9) + (lane << 3)))

  // ---- stage ----
  if (t < NE) dst_s[t] = edge_index[NE + t];
  for (int idx = t; idx < 64 * 32; idx += 256) {     // nf (K=18 pad 32); rows 54..63 zero
    int r = idx >> 5, c = idx & 31;
    m_s[r][c] = (r < NN && c < FN) ? f2b(nf[(size_t)b * (NN * FN) + r * FN + c]) : (short)0;
  }
  for (int idx = t; idx < 80 * 16; idx += 256)       // m K-pad cols 48..63
    m_s[idx >> 4][48 + (idx & 15)] = 0;
  for (int idx = t; idx < 48 * 8; idx += 256)        // m_t pad cols 144..151
    m_t[(idx >> 3) * TS + 144 + (idx & 7)] = 0;
  if (t < 8) m_t[48 * TS + t] = 0;

  // ---- per-wave edge tiles & register frags ----
  const int mt0 = w, mt2 = 5 + w;
  int rs0 = edge_index[mt0 * 16 + lx] * HS, rd0 = edge_index[NE + mt0 * 16 + lx] * HS;
  int rs1 = 0, rd1 = 0;
  if (w == 0) { rs1 = edge_index[64 + lx] * HS; rd1 = edge_index[NE + 64 + lx] * HS; }
  int rs2 = edge_index[mt2 * 16 + lx] * HS, rd2 = edge_index[NE + mt2 * 16 + lx] * HS;

  auto ldef = [&](int mt) -> v8s {   // ef frag: lg==0 lanes hold ef[e][0..4]
    v8s r = {0, 0, 0, 0, 0, 0, 0, 0};
    if (lg == 0) {
      const float* ep = efx + (size_t)b * (NE * FE) + (mt * 16 + lx) * FE;
      r[0] = f2b(ep[0]); r[1] = f2b(ep[1]); r[2] = f2b(ep[2]);
      r[3] = f2b(ep[3]); r[4] = f2b(ep[4]);
    }
    return r;
  };
  v8s aef0 = ldef(mt0);
  v8s aef1 = (w == 0) ? ldef(4) : (v8s){0,0,0,0,0,0,0,0};
  v8s aef2 = ldef(mt2);

  __syncthreads();

  const short* h0 = &h_s[0][0];
  const int node = w * 16 + lx;       // this lane's owned node (swapped C: col=lx)
  const int nrd = (node < NN) ? node : 0;

  // ---- input proj (swapped: lane holds 12 ch of node) ----
  {
    v8s a = *(const v8s*)(&m_s[node][koff]);
    #pragma unroll
    for (int ct = 0; ct < 3; ++ct) {
      v4f c = *(const v4f*)(b_node + ct * 16 + lg4);
      c = MFMA(LD8(ct), a, c);
      if (node < NN) st4m(&h_s[node][ct * 16 + lg4], c);
    }
  }
  __syncthreads();

  for (int l = 0; l < NL; ++l) {
    const int FB = 3 + l * 33;
    // hoist msg-phase frags (reused over 2-3 tiles)
    v8s bw1[3][3], bwe[3], bw2[2][3];
    #pragma unroll
    for (int ks = 0; ks < 3; ++ks)
      #pragma unroll
      for (int ct = 0; ct < 3; ++ct) bw1[ks][ct] = LD8(FB + ks * 3 + ct);
    #pragma unroll
    for (int ct = 0; ct < 3; ++ct) bwe[ct] = LD8(FB + 9 + ct);
    #pragma unroll
    for (int ks = 0; ks < 2; ++ks)
      #pragma unroll
      for (int ct = 0; ct < 3; ++ct) bw2[ks][ct] = LD8(FB + 12 + ks * 3 + ct);
    float bm2[3];
    #pragma unroll
    for (int nt = 0; nt < 3; ++nt) bm2[nt] = msg_b2[(size_t)l * HD + nt * 16 + lx];

    // ---- msg1 (swapped) + msg2 (non-swapped -> m_t) per tile ----
    auto do_msg = [&](int mt, int slot, v8s aef, int rs, int rd) {
      v4f c0 = *(const v4f*)(mb1 + l * HD + lg4);
      v4f c1 = *(const v4f*)(mb1 + l * HD + 16 + lg4);
      v4f c2 = *(const v4f*)(mb1 + l * HD + 32 + lg4);
      c0 = MFMA(bwe[0], aef, c0);
      c1 = MFMA(bwe[1], aef, c1);
      c2 = MFMA(bwe[2], aef, c2);
      #pragma unroll
      for (int ks = 0; ks < 3; ++ks) {
        int kk = ks * 32 + koff;
        const short* p = (kk < HD) ? (h0 + rs + kk) : (h0 + rd + (kk - HD));
        v8s a = *(const v8s*)p;
        c0 = MFMA(bw1[ks][0], a, c0);
        c1 = MFMA(bw1[ks][1], a, c1);
        c2 = MFMA(bw1[ks][2], a, c2);
      }
      short* mr = &m_s[slot + lx][0];
      st4m(mr + lg4, c0);
      st4m(mr + 16 + lg4, c1);
      st4m(mr + 32 + lg4, c2);
      // msg2: A = m row (written by this wave), B = msg_w2 frags; out -> m_t transposed
      v8s a0 = *(const v8s*)(mr + koff);
      v8s a1 = *(const v8s*)(mr + 32 + koff);
      #pragma unroll
      for (int nt = 0; nt < 3; ++nt) {
        v4f c = {bm2[nt], bm2[nt], bm2[nt], bm2[nt]};
        c = MFMA(a0, bw2[0][nt], c);
        c = MFMA(a1, bw2[1][nt], c);
        uint2 u;
        u.x = cvt_pk(mish_f(c[0]), mish_f(c[1]));
        u.y = cvt_pk(mish_f(c[2]), mish_f(c[3]));
        *(uint2*)(&m_t[(nt * 16 + lx) * TS + mt * 16 + lg4]) = u;
      }
    };
    do_msg(mt0, w * 16, aef0, rs0, rd0);
    if (w == 0) do_msg(4, 64, aef1, rs1, rd1);
    do_msg(mt2, w * 16, aef2, rs2, rd2);
    __syncthreads();   // barrier 1: m_t complete

    // ---- agg via MFMA (round-4-proven): agg_s[node][ch] ----
    {
      v8s sfr[5];
      #pragma unroll
      for (int kt = 0; kt < 5; ++kt) {
        v8s sv = {0, 0, 0, 0, 0, 0, 0, 0};
        #pragma unroll
        for (int j = 0; j < 8; ++j) {
          int e = kt * 32 + koff + j;
          if (e < NE && dst_s[e] == node) sv[j] = (short)0x3F80;  // bf16 1.0
        }
        sfr[kt] = sv;
      }
      #pragma unroll
      for (int ct = 0; ct < 3; ++ct) {
        v4f c = {0.f, 0.f, 0.f, 0.f};
        #pragma unroll
        for (int kt = 0; kt < 5; ++kt) {
          v8s a = *(const v8s*)(&m_t[(ct * 16 + lx) * TS + kt * 32 + koff]);
          c = MFMA(a, sfr[kt], c);
        }
        if (node < NN) st4v(&agg_s[node][ct * 16 + lg4], c);
      }
    }
    // ---- upd1 (swapped; same wave) ----
    {
      v4f c0 = *(const v4f*)(upd_b1 + l * HD + lg4);
      v4f c1 = *(const v4f*)(upd_b1 + l * HD + 16 + lg4);
      v4f c2 = *(const v4f*)(upd_b1 + l * HD + 32 + lg4);
      #pragma unroll
      for (int ks = 0; ks < 3; ++ks) {
        int kk = ks * 32 + koff;
        const short* p = (kk < HD) ? (&h_s[nrd][kk]) : (&agg_s[nrd][kk - HD]);
        v8s a = *(const v8s*)p;
        c0 = MFMA(LD8(FB + 18 + ks * 3 + 0), a, c0);
        c1 = MFMA(LD8(FB + 18 + ks * 3 + 1), a, c1);
        c2 = MFMA(LD8(FB + 18 + ks * 3 + 2), a, c2);
      }
      short* ur = &m_s[node][0];
      st4m(ur + lg4, c0);
      st4m(ur + 16 + lg4, c1);
      st4m(ur + 32 + lg4, c2);
      // ---- upd2 (swapped) + residual + LN ----
      v8s a0 = *(const v8s*)(ur + koff);
      v8s a1 = *(const v8s*)(ur + 32 + koff);
      v4f cc[3];
      #pragma unroll
      for (int ct = 0; ct < 3; ++ct) {
        v4f c = *(const v4f*)(upd_b2 + l * HD + ct * 16 + lg4);
        c = MFMA(LD8(FB + 27 + ct), a0, c);
        c = MFMA(LD8(FB + 30 + ct), a1, c);
        cc[ct] = c;
      }
      float x[3][4];
      float s = 0.f, q = 0.f;
      #pragma unroll
      for (int ct = 0; ct < 3; ++ct) {
        uint2 hv = *(const uint2*)(&h_s[nrd][ct * 16 + lg4]);
        x[ct][0] = cc[ct][0] + __uint_as_float(hv.x << 16);
        x[ct][1] = cc[ct][1] + __uint_as_float(hv.x & 0xFFFF0000u);
        x[ct][2] = cc[ct][2] + __uint_as_float(hv.y << 16);
        x[ct][3] = cc[ct][3] + __uint_as_float(hv.y & 0xFFFF0000u);
        #pragma unroll
        for (int r = 0; r < 4; ++r) { s += x[ct][r]; q = fmaf(x[ct][r], x[ct][r], q); }
      }
      s += __shfl_xor(s, 16); s += __shfl_xor(s, 32);
      q += __shfl_xor(q, 16); q += __shfl_xor(q, 32);
      float mu = s * (1.f / HD);
      float var = q * (1.f / HD) - mu * mu;
      float rsg = rsqrtf(var + 1e-5f);
      float* onode = out + (size_t)NGR * NOUT + (size_t)b * (NN * HD);
      #pragma unroll
      for (int ct = 0; ct < 3; ++ct) {
        v4f g4 = *(const v4f*)(ln_g + l * HD + ct * 16 + lg4);
        v4f b4 = *(const v4f*)(ln_b + l * HD + ct * 16 + lg4);
        v4f y;
        #pragma unroll
        for (int r = 0; r < 4; ++r) y[r] = (x[ct][r] - mu) * rsg * g4[r] + b4[r];
        if (node < NN) {
          st4v(&h_s[node][ct * 16 + lg4], y);
          if (l == NL - 1) *(v4f*)(onode + node * HD + ct * 16 + lg4) = y;
        }
      }
    }
    __syncthreads();   // barrier 2: h ready for next layer / pooling
  }

  // ---- pooling ----
  if (t < 96) {
    int half = t >= HD;
    int ch = t - half * HD;
    float smv = 0.f, mx = -3.0e38f;
    int n0 = half * 27;
    for (int n = n0; n < n0 + 27; ++n) {
      float v = b2f(h_s[n][ch]);
      smv += v; mx = fmaxf(mx, v);
    }
    psum[t] = smv; pmax[t] = mx;
  }
  __syncthreads();
  if (t < HD) {
    pooled[t] = (psum[t] + psum[HD + t]) * (1.f / NN);
    pooled[HD + t] = fmaxf(pmax[t], pmax[HD + t]);
  }
  __syncthreads();

  // ---- output MLP (fp32) ----
  if (t < NOUT) {
    float a = b_out1[t];
    #pragma unroll 8
    for (int k = 0; k < 2 * HD; ++k) a = fmaf(pooled[k], w_out1[k * NOUT + t], a);
    o1[t] = mish_f(a);
  }
  __syncthreads();
  if (t < NOUT) {
    float a = b_out2[t];
    #pragma unroll 8
    for (int k = 0; k < NOUT; ++k) a = fmaf(o1[k], w_out2[k * NOUT + t], a);
    out[(size_t)b * NOUT + t] = a;
  }
}

extern "C" void kernel_launch(void* const* d_in, const int* in_sizes, int n_in,
                              void* d_out, int out_size, void* d_ws, size_t ws_size,
                              hipStream_t stream) {
  const float* nf     = (const float*)d_in[0];
  const float* ef     = (const float*)d_in[1];
  const float* w_node = (const float*)d_in[2];
  const float* b_node = (const float*)d_in[3];
  const float* w_edge = (const float*)d_in[4];
  const float* b_edge = (const float*)d_in[5];
  const float* msg_w1 = (const float*)d_in[6];
  const float* msg_b1 = (const float*)d_in[7];
  const float* msg_w2 = (const float*)d_in[8];
  const float* msg_b2 = (const float*)d_in[9];
  const float* upd_w1 = (const float*)d_in[10];
  const float* upd_b1 = (const float*)d_in[11];
  const float* upd_w2 = (const float*)d_in[12];
  const float* upd_b2 = (const float*)d_in[13];
  const float* ln_g   = (const float*)d_in[14];
  const float* ln_b   = (const float*)d_in[15];
  const float* w_out1 = (const float*)d_in[16];
  const float* b_out1 = (const float*)d_in[17];
  const float* w_out2 = (const float*)d_in[18];
  const float* b_out2 = (const float*)d_in[19];
  const int* edge_index = (const int*)d_in[20];

  float* mb1   = (float*)d_ws;                   // [0, 768)
  short* frags = (short*)((char*)d_ws + 1024);   // 102*1024 B -> total 105,472 B (proven)

  gnn_setup<<<32, 256, 0, stream>>>(w_node, w_edge, b_edge, msg_w1, msg_b1,
                                    msg_w2, upd_w1, upd_w2, mb1, frags);
  gnn_main<<<NGR, 256, 0, stream>>>(nf, ef, b_node, msg_b2, upd_b1, upd_b2,
                                    ln_g, ln_b, w_out1, b_out1, w_out2, b_out2,
                                    edge_index, mb1, frags, (float*)d_out);
}

// Round 8
// 446.553 us; speedup vs baseline: 1.2267x; 1.2267x over previous
//
#include <hip/hip_runtime.h>

#define NGR 8192
#define NN 54
#define NE 144
#define FN 18
#define FE 5
#define HD 48
#define NOUT 80
#define NL 3
#define HS 56    // h/agg row stride (shorts): 112B
#define MS 72    // m row stride (shorts): 144B
#define TS 152   // m_t row stride (shorts): 304B
#define NFRAG 102

typedef short v8s __attribute__((ext_vector_type(8)));
typedef float v4f __attribute__((ext_vector_type(4)));

#define MFMA(a, b, c) __builtin_amdgcn_mfma_f32_16x16x32_bf16((a), (b), (c), 0, 0, 0)

static __device__ __forceinline__ float mish_f(float x) {
  // x * u/(u+2), u = t(t+2), t = e^min(x,30): exact mish for x<=30, ==x beyond
  float t = __expf(fminf(x, 30.f));
  float u = t * (t + 2.f);
  return x * u * __builtin_amdgcn_rcpf(u + 2.f);
}
static __device__ __forceinline__ short f2b(float x) {  // fp32->bf16 RNE (setup/scalar paths)
  union { float f; unsigned u; } v; v.f = x;
  unsigned r = v.u + 0x7FFFu + ((v.u >> 16) & 1u);
  return (short)(r >> 16);
}
static __device__ __forceinline__ float b2f(short s) {
  union { unsigned u; float f; } v; v.u = ((unsigned)(unsigned short)s) << 16;
  return v.f;
}
static __device__ __forceinline__ unsigned cvt_pk(float lo, float hi) {
  unsigned r;
  asm("v_cvt_pk_bf16_f32 %0, %1, %2" : "=v"(r) : "v"(lo), "v"(hi));
  return r;
}
static __device__ __forceinline__ void st4v(short* p, v4f y) {   // 4 ch -> b64 store
  uint2 u; u.x = cvt_pk(y[0], y[1]); u.y = cvt_pk(y[2], y[3]);
  *(uint2*)p = u;
}
static __device__ __forceinline__ void st4m(short* p, v4f c) {   // mish then b64 store
  v4f y; y[0] = mish_f(c[0]); y[1] = mish_f(c[1]); y[2] = mish_f(c[2]); y[3] = mish_f(c[3]);
  st4v(p, y);
}

// ---------------- setup: weight fragment prepack + folded msg bias (proven, 102 frags) ----------------
__global__ void gnn_setup(const float* __restrict__ w_node,
                          const float* __restrict__ w_edge,
                          const float* __restrict__ b_edge,
                          const float* __restrict__ msg_w1,
                          const float* __restrict__ msg_b1,
                          const float* __restrict__ msg_w2,
                          const float* __restrict__ upd_w1,
                          const float* __restrict__ upd_w2,
                          float* __restrict__ mb1, short* __restrict__ frags) {
  const int t = threadIdx.x;
  if (blockIdx.x == 0) {
    for (int idx = t; idx < NL * HD; idx += 256) {
      int l = idx / HD, c = idx % HD;
      float s = msg_b1[l * HD + c];
      for (int k = 0; k < HD; ++k)
        s += b_edge[k] * msg_w1[(l * 144 + 96 + k) * HD + c];
      mb1[idx] = s;
    }
  }
  // frag f, lane, elem j holds W[ks*32 + (lane>>4)*8 + j][ct*16 + (lane&15)]
  for (int eid = blockIdx.x * 256 + t; eid < NFRAG * 512; eid += gridDim.x * 256) {
    int f = eid >> 9, r = eid & 511;
    int lane = r >> 3, j = r & 7;
    int kk = ((lane >> 4) << 3) + j;
    int colq = lane & 15;
    float val = 0.f;
    if (f < 3) {                          // w_node (K=18 pad 32), ct=f
      int c = f * 16 + colq;
      if (kk < FN) val = w_node[kk * HD + c];
    } else {
      int g = f - 3, l = g / 33, o = g % 33;
      if (o < 9) {                        // msg_w1 rows 0..95
        int ks = o / 3, ct = o % 3, c = ct * 16 + colq, k = ks * 32 + kk;
        val = msg_w1[(l * 144 + k) * HD + c];
      } else if (o < 12) {                // W_eff = w_edge @ msg_w1[96:144] (K=5 pad 32)
        int ct = o - 9, c = ct * 16 + colq;
        if (kk < FE) {
          float s = 0.f;
          for (int k2 = 0; k2 < HD; ++k2)
            s += w_edge[kk * HD + k2] * msg_w1[(l * 144 + 96 + k2) * HD + c];
          val = s;
        }
      } else if (o < 18) {                // msg_w2 (K=48 pad 64)
        int oo = o - 12, ks = oo / 3, ct = oo % 3, c = ct * 16 + colq, k = ks * 32 + kk;
        if (k < HD) val = msg_w2[(l * HD + k) * HD + c];
      } else if (o < 27) {                // upd_w1 (K=96)
        int oo = o - 18, ks = oo / 3, ct = oo % 3, c = ct * 16 + colq, k = ks * 32 + kk;
        val = upd_w1[(l * 96 + k) * HD + c];
      } else {                            // upd_w2 (K=48 pad 64)
        int oo = o - 27, ks = oo / 3, ct = oo % 3, c = ct * 16 + colq, k = ks * 32 + kk;
        if (k < HD) val = upd_w2[(l * HD + k) * HD + c];
      }
    }
    frags[eid] = f2b(val);
  }
}

// ---------------- main: one block (4 waves) per graph ----------------
__global__ __launch_bounds__(256, 4) void gnn_main(
    const float* __restrict__ nf, const float* __restrict__ efx,
    const float* __restrict__ b_node,
    const float* __restrict__ msg_b2,
    const float* __restrict__ upd_b1, const float* __restrict__ upd_b2,
    const float* __restrict__ ln_g, const float* __restrict__ ln_b,
    const float* __restrict__ w_out1, const float* __restrict__ b_out1,
    const float* __restrict__ w_out2, const float* __restrict__ b_out2,
    const int* __restrict__ edge_index,
    const float* __restrict__ mb1, const short* __restrict__ frags,
    float* __restrict__ out)
{
  __shared__ __align__(16) short h_s[NN][HS];        // 6048 B
  __shared__ __align__(16) short agg_s[NN][HS];      // 6048 B
  __shared__ __align__(16) short m_s[80][MS];        // 11520 B
  __shared__ __align__(16) short m_t[48 * TS + 8];   // 14608 B
  __shared__ int dst_s[NE];
  __shared__ float psum[96], pmax[96], pooled[96], o1[NOUT];

  const int b = blockIdx.x;
  const int t = threadIdx.x;
  const int lane = t & 63;
  const int w = t >> 6;
  const int lx = lane & 15;
  const int lg = lane >> 4;
  const int koff = lg << 3;
  const int lg4 = lg << 2;

#define LD8(f) (*(const v8s*)(frags + ((size_t)(f) << 9) + (lane << 3)))

  // ---- stage ----
  if (t < NE) dst_s[t] = edge_index[NE + t];
  for (int idx = t; idx < 64 * 32; idx += 256) {     // nf (K=18 pad 32); rows 54..63 zero
    int r = idx >> 5, c = idx & 31;
    m_s[r][c] = (r < NN && c < FN) ? f2b(nf[(size_t)b * (NN * FN) + r * FN + c]) : (short)0;
  }
  for (int idx = t; idx < 80 * 16; idx += 256)       // m K-pad cols 48..63
    m_s[idx >> 4][48 + (idx & 15)] = 0;
  for (int idx = t; idx < 48 * 8; idx += 256)        // m_t pad cols 144..151
    m_t[(idx >> 3) * TS + 144 + (idx & 7)] = 0;
  if (t < 8) m_t[48 * TS + t] = 0;

  // ---- per-wave edge tiles & register frags ----
  const int mt0 = w, mt2 = 5 + w;
  int rs0 = edge_index[mt0 * 16 + lx] * HS, rd0 = edge_index[NE + mt0 * 16 + lx] * HS;
  int rs1 = 0, rd1 = 0;
  if (w == 0) { rs1 = edge_index[64 + lx] * HS; rd1 = edge_index[NE + 64 + lx] * HS; }
  int rs2 = edge_index[mt2 * 16 + lx] * HS, rd2 = edge_index[NE + mt2 * 16 + lx] * HS;

  auto ldef = [&](int mt) -> v8s {   // ef frag: lg==0 lanes hold ef[e][0..4]
    v8s r = {0, 0, 0, 0, 0, 0, 0, 0};
    if (lg == 0) {
      const float* ep = efx + (size_t)b * (NE * FE) + (mt * 16 + lx) * FE;
      r[0] = f2b(ep[0]); r[1] = f2b(ep[1]); r[2] = f2b(ep[2]);
      r[3] = f2b(ep[3]); r[4] = f2b(ep[4]);
    }
    return r;
  };
  v8s aef0 = ldef(mt0);
  v8s aef1 = (w == 0) ? ldef(4) : (v8s){0,0,0,0,0,0,0,0};
  v8s aef2 = ldef(mt2);

  __syncthreads();

  const short* h0 = &h_s[0][0];
  const int node = w * 16 + lx;       // this lane's owned node (swapped C: col=lx)
  const int nrd = (node < NN) ? node : 0;

  // ---- input proj (swapped: lane holds 12 ch of node) ----
  {
    v8s a = *(const v8s*)(&m_s[node][koff]);
    #pragma unroll
    for (int ct = 0; ct < 3; ++ct) {
      v4f c = *(const v4f*)(b_node + ct * 16 + lg4);
      c = MFMA(LD8(ct), a, c);
      if (node < NN) st4m(&h_s[node][ct * 16 + lg4], c);
    }
  }
  __syncthreads();

  for (int l = 0; l < NL; ++l) {
    const int FB = 3 + l * 33;
    float bm2[3];
    #pragma unroll
    for (int nt = 0; nt < 3; ++nt) bm2[nt] = msg_b2[(size_t)l * HD + nt * 16 + lx];

    // ---- msg1 (swapped) + msg2 (non-swapped -> m_t) per tile; frags read inline ----
    auto do_msg = [&](int mt, int slot, v8s aef, int rs, int rd) {
      v4f c0 = *(const v4f*)(mb1 + l * HD + lg4);
      v4f c1 = *(const v4f*)(mb1 + l * HD + 16 + lg4);
      v4f c2 = *(const v4f*)(mb1 + l * HD + 32 + lg4);
      c0 = MFMA(LD8(FB + 9),  aef, c0);
      c1 = MFMA(LD8(FB + 10), aef, c1);
      c2 = MFMA(LD8(FB + 11), aef, c2);
      #pragma unroll
      for (int ks = 0; ks < 3; ++ks) {
        int kk = ks * 32 + koff;
        const short* p = (kk < HD) ? (h0 + rs + kk) : (h0 + rd + (kk - HD));
        v8s a = *(const v8s*)p;
        c0 = MFMA(LD8(FB + ks * 3 + 0), a, c0);
        c1 = MFMA(LD8(FB + ks * 3 + 1), a, c1);
        c2 = MFMA(LD8(FB + ks * 3 + 2), a, c2);
      }
      short* mr = &m_s[slot + lx][0];
      st4m(mr + lg4, c0);
      st4m(mr + 16 + lg4, c1);
      st4m(mr + 32 + lg4, c2);
      // msg2: A = m row (written by this wave), B = msg_w2 frags; out -> m_t transposed
      v8s a0 = *(const v8s*)(mr + koff);
      v8s a1 = *(const v8s*)(mr + 32 + koff);
      #pragma unroll
      for (int nt = 0; nt < 3; ++nt) {
        v4f c = {bm2[nt], bm2[nt], bm2[nt], bm2[nt]};
        c = MFMA(a0, LD8(FB + 12 + nt), c);
        c = MFMA(a1, LD8(FB + 15 + nt), c);
        uint2 u;
        u.x = cvt_pk(mish_f(c[0]), mish_f(c[1]));
        u.y = cvt_pk(mish_f(c[2]), mish_f(c[3]));
        *(uint2*)(&m_t[(nt * 16 + lx) * TS + mt * 16 + lg4]) = u;
      }
    };
    do_msg(mt0, w * 16, aef0, rs0, rd0);
    if (w == 0) do_msg(4, 64, aef1, rs1, rd1);
    do_msg(mt2, w * 16, aef2, rs2, rd2);
    __syncthreads();   // barrier 1: m_t complete

    // ---- agg via MFMA: agg_s[node][ch]; S-frags built in-loop (r5-proven placement) ----
    {
      v8s sfr[5];
      #pragma unroll
      for (int kt = 0; kt < 5; ++kt) {
        v8s sv = {0, 0, 0, 0, 0, 0, 0, 0};
        #pragma unroll
        for (int j = 0; j < 8; ++j) {
          int e = kt * 32 + koff + j;
          if (e < NE && dst_s[e] == node) sv[j] = (short)0x3F80;  // bf16 1.0
        }
        sfr[kt] = sv;
      }
      #pragma unroll
      for (int ct = 0; ct < 3; ++ct) {
        v4f c = {0.f, 0.f, 0.f, 0.f};
        #pragma unroll
        for (int kt = 0; kt < 5; ++kt) {
          v8s a = *(const v8s*)(&m_t[(ct * 16 + lx) * TS + kt * 32 + koff]);
          c = MFMA(a, sfr[kt], c);
        }
        if (node < NN) st4v(&agg_s[node][ct * 16 + lg4], c);
      }
    }
    // ---- upd1 (swapped; same wave) ----
    {
      v4f c0 = *(const v4f*)(upd_b1 + l * HD + lg4);
      v4f c1 = *(const v4f*)(upd_b1 + l * HD + 16 + lg4);
      v4f c2 = *(const v4f*)(upd_b1 + l * HD + 32 + lg4);
      #pragma unroll
      for (int ks = 0; ks < 3; ++ks) {
        int kk = ks * 32 + koff;
        const short* p = (kk < HD) ? (&h_s[nrd][kk]) : (&agg_s[nrd][kk - HD]);
        v8s a = *(const v8s*)p;
        c0 = MFMA(LD8(FB + 18 + ks * 3 + 0), a, c0);
        c1 = MFMA(LD8(FB + 18 + ks * 3 + 1), a, c1);
        c2 = MFMA(LD8(FB + 18 + ks * 3 + 2), a, c2);
      }
      short* ur = &m_s[node][0];
      st4m(ur + lg4, c0);
      st4m(ur + 16 + lg4, c1);
      st4m(ur + 32 + lg4, c2);
      // ---- upd2 (swapped) + residual + LN ----
      v8s a0 = *(const v8s*)(ur + koff);
      v8s a1 = *(const v8s*)(ur + 32 + koff);
      v4f cc[3];
      #pragma unroll
      for (int ct = 0; ct < 3; ++ct) {
        v4f c = *(const v4f*)(upd_b2 + l * HD + ct * 16 + lg4);
        c = MFMA(LD8(FB + 27 + ct), a0, c);
        c = MFMA(LD8(FB + 30 + ct), a1, c);
        cc[ct] = c;
      }
      float x[3][4];
      float s = 0.f, q = 0.f;
      #pragma unroll
      for (int ct = 0; ct < 3; ++ct) {
        uint2 hv = *(const uint2*)(&h_s[nrd][ct * 16 + lg4]);
        x[ct][0] = cc[ct][0] + __uint_as_float(hv.x << 16);
        x[ct][1] = cc[ct][1] + __uint_as_float(hv.x & 0xFFFF0000u);
        x[ct][2] = cc[ct][2] + __uint_as_float(hv.y << 16);
        x[ct][3] = cc[ct][3] + __uint_as_float(hv.y & 0xFFFF0000u);
        #pragma unroll
        for (int r = 0; r < 4; ++r) { s += x[ct][r]; q = fmaf(x[ct][r], x[ct][r], q); }
      }
      s += __shfl_xor(s, 16); s += __shfl_xor(s, 32);
      q += __shfl_xor(q, 16); q += __shfl_xor(q, 32);
      float mu = s * (1.f / HD);
      float var = q * (1.f / HD) - mu * mu;
      float rsg = rsqrtf(var + 1e-5f);
      float* onode = out + (size_t)NGR * NOUT + (size_t)b * (NN * HD);
      #pragma unroll
      for (int ct = 0; ct < 3; ++ct) {
        v4f g4 = *(const v4f*)(ln_g + l * HD + ct * 16 + lg4);
        v4f b4 = *(const v4f*)(ln_b + l * HD + ct * 16 + lg4);
        v4f y;
        #pragma unroll
        for (int r = 0; r < 4; ++r) y[r] = (x[ct][r] - mu) * rsg * g4[r] + b4[r];
        if (node < NN) {
          st4v(&h_s[node][ct * 16 + lg4], y);
          if (l == NL - 1) *(v4f*)(onode + node * HD + ct * 16 + lg4) = y;
        }
      }
    }
    __syncthreads();   // barrier 2: h ready for next layer / pooling
  }

  // ---- pooling ----
  if (t < 96) {
    int half = t >= HD;
    int ch = t - half * HD;
    float smv = 0.f, mx = -3.0e38f;
    int n0 = half * 27;
    for (int n = n0; n < n0 + 27; ++n) {
      float v = b2f(h_s[n][ch]);
      smv += v; mx = fmaxf(mx, v);
    }
    psum[t] = smv; pmax[t] = mx;
  }
  __syncthreads();
  if (t < HD) {
    pooled[t] = (psum[t] + psum[HD + t]) * (1.f / NN);
    pooled[HD + t] = fmaxf(pmax[t], pmax[HD + t]);
  }
  __syncthreads();

  // ---- output MLP (fp32) ----
  if (t < NOUT) {
    float a = b_out1[t];
    #pragma unroll 8
    for (int k = 0; k < 2 * HD; ++k) a = fmaf(pooled[k], w_out1[k * NOUT + t], a);
    o1[t] = mish_f(a);
  }
  __syncthreads();
  if (t < NOUT) {
    float a = b_out2[t];
    #pragma unroll 8
    for (int k = 0; k < NOUT; ++k) a = fmaf(o1[k], w_out2[k * NOUT + t], a);
    out[(size_t)b * NOUT + t] = a;
  }
}

extern "C" void kernel_launch(void* const* d_in, const int* in_sizes, int n_in,
                              void* d_out, int out_size, void* d_ws, size_t ws_size,
                              hipStream_t stream) {
  const float* nf     = (const float*)d_in[0];
  const float* ef     = (const float*)d_in[1];
  const float* w_node = (const float*)d_in[2];
  const float* b_node = (const float*)d_in[3];
  const float* w_edge = (const float*)d_in[4];
  const float* b_edge = (const float*)d_in[5];
  const float* msg_w1 = (const float*)d_in[6];
  const float* msg_b1 = (const float*)d_in[7];
  const float* msg_w2 = (const float*)d_in[8];
  const float* msg_b2 = (const float*)d_in[9];
  const float* upd_w1 = (const float*)d_in[10];
  const float* upd_b1 = (const float*)d_in[11];
  const float* upd_w2 = (const float*)d_in[12];
  const float* upd_b2 = (const float*)d_in[13];
  const float* ln_g   = (const float*)d_in[14];
  const float* ln_b   = (const float*)d_in[15];
  const float* w_out1 = (const float*)d_in[16];
  const float* b_out1 = (const float*)d_in[17];
  const float* w_out2 = (const float*)d_in[18];
  const float* b_out2 = (const float*)d_in[19];
  const int* edge_index = (const int*)d_in[20];

  float* mb1   = (float*)d_ws;                   // [0, 768)
  short* frags = (short*)((char*)d_ws + 1024);   // 102*1024 B -> total 105,472 B (proven)

  gnn_setup<<<32, 256, 0, stream>>>(w_node, w_edge, b_edge, msg_w1, msg_b1,
                                    msg_w2, upd_w1, upd_w2, mb1, frags);
  gnn_main<<<NGR, 256, 0, stream>>>(nf, ef, b_node, msg_b2, upd_b1, upd_b2,
                                    ln_g, ln_b, w_out1, b_out1, w_out2, b_out2,
                                    edge_index, mb1, frags, (float*)d_out);
}